// Round 9
// baseline (1813.327 us; speedup 1.0000x reference)
//
#include <hip/hip_runtime.h>
#include <hip/hip_bf16.h>
#include <stdint.h>

#define NN 8192
#define DD 512
#define KK 31
#define HH 256
#define OO 16
#define SBATCH 2048
#define NE (NN*KK)    // 253952 directed edges
#define CTARGET 64
#define CCAP 128

typedef __attribute__((ext_vector_type(8))) short bf16x8;
typedef __attribute__((ext_vector_type(4))) float f32x4;

__device__ __forceinline__ float bf2f(__hip_bfloat16 v){ return __bfloat162float(v); }

__device__ __forceinline__ void async_lds16(const void* g, void* l){
  __builtin_amdgcn_global_load_lds((const __attribute__((address_space(1))) unsigned int*)g,
                                   (__attribute__((address_space(3))) unsigned int*)l, 16, 0, 0);
}

// runtime input-dtype flag: 1 = inputs are float32, 0 = inputs are bf16
__device__ __forceinline__ float ldf(const void* p, size_t i, int f){
  return f ? ((const float*)p)[i] : bf2f(((const __hip_bfloat16*)p)[i]);
}

// block 0: dtype-detect -> flag ; blocks 1..32: zero deg/in_count/cursor
__global__ void init_kernel(const void* feat, int* flag, double* deg, int* in_count, int* cursor){
  const int tid = threadIdx.x;
  if (blockIdx.x == 0){
    __shared__ int red[256];
    int cnt = 0;
    const __hip_bfloat16* fb = (const __hip_bfloat16*)feat;
    for (int m = 0; m < 16; ++m){
      float v = bf2f(fb[tid*16 + m]);
      if (!(fabsf(v) <= 100.f)) cnt++;
    }
    red[tid] = cnt; __syncthreads();
    for (int s = 128; s > 0; s >>= 1){ if (tid < s) red[tid] += red[tid+s]; __syncthreads(); }
    if (tid == 0) *flag = (red[0] > 40) ? 1 : 0;
  } else {
    int i = (blockIdx.x - 1)*256 + tid;
    if (i < NN){ deg[i] = 0.0; in_count[i] = 0; cursor[i] = 0; }
  }
}

// ---------------- fp32 NT GEMM, np/BLAS-exact chain; 128x128 tile, 8x8/thread ----------------
// C[M][OUTW] = A[M][512] @ W[OUTW][512]^T + b ; per-C-element single fp32 acc, k ascending.
template<bool A_RAW, bool RELU, int OUTW>
__global__ void __launch_bounds__(256)
gemm_nt_f32(const void* Ap, const void* W, const void* bias, float* C, const int* flagp){
  const int f = *flagp;
  __shared__ float As[16*132];   // [k][m] transposed
  __shared__ float Bs[16*132];   // [k][n]
  const int tid = threadIdx.x;
  const int tx = tid & 15, ty = tid >> 4;
  const int bm = blockIdx.y*128, bn = blockIdx.x*128;
  float acc[8][8] = {};
  for (int k0 = 0; k0 < DD; k0 += 16){
    #pragma unroll
    for (int p = 0; p < 2; ++p){
      int chunk = p*256 + tid;        // 0..511
      int m = chunk >> 2, c = chunk & 3;
      float v0,v1,v2,v3;
      if (A_RAW){
        size_t o = (size_t)(bm+m)*DD + k0 + c*4;
        v0=ldf(Ap,o,f); v1=ldf(Ap,o+1,f); v2=ldf(Ap,o+2,f); v3=ldf(Ap,o+3,f);
      } else {
        const float* a = (const float*)Ap + (size_t)(bm+m)*DD + k0 + c*4;
        v0=a[0]; v1=a[1]; v2=a[2]; v3=a[3];
      }
      As[(c*4+0)*132+m]=v0; As[(c*4+1)*132+m]=v1; As[(c*4+2)*132+m]=v2; As[(c*4+3)*132+m]=v3;
      size_t ow = (size_t)(bn+m)*DD + k0 + c*4;
      Bs[(c*4+0)*132+m]=ldf(W,ow,f);   Bs[(c*4+1)*132+m]=ldf(W,ow+1,f);
      Bs[(c*4+2)*132+m]=ldf(W,ow+2,f); Bs[(c*4+3)*132+m]=ldf(W,ow+3,f);
    }
    __syncthreads();
    #pragma unroll
    for (int kk = 0; kk < 16; ++kk){
      const float4* Av = (const float4*)&As[kk*132 + ty*8];
      const float4* Bv = (const float4*)&Bs[kk*132 + tx*8];
      float4 a0 = Av[0], a1 = Av[1], b0 = Bv[0], b1 = Bv[1];
      float a[8] = {a0.x,a0.y,a0.z,a0.w,a1.x,a1.y,a1.z,a1.w};
      float b[8] = {b0.x,b0.y,b0.z,b0.w,b1.x,b1.y,b1.z,b1.w};
      #pragma unroll
      for (int i = 0; i < 8; ++i)
        #pragma unroll
        for (int j = 0; j < 8; ++j)
          acc[i][j] = fmaf(a[i], b[j], acc[i][j]);
    }
    __syncthreads();
  }
  #pragma unroll
  for (int i = 0; i < 8; ++i)
    #pragma unroll
    for (int j = 0; j < 8; ++j){
      int m = bm + ty*8 + i, n = bn + tx*8 + j;
      float v = acc[i][j] + ldf(bias, n, f);
      if (RELU && v < 0.f) v = 0.f;
      C[(size_t)m*OUTW + n] = v;
    }
}

// ---------------- np.linalg.norm emulation (fp32, numpy pairwise + AVX512 lane tree) ------------
// one thread per row; in-place h -> h/max(norm,1e-12); also emits bf16 copy
__global__ void norm_np_kernel(float* emb, __hip_bfloat16* embbf){
  int row = blockIdx.x*256 + threadIdx.x;
  if (row >= NN) return;
  float* h = emb + (size_t)row*DD;
  __hip_bfloat16* hb = embbf + (size_t)row*DD;
  float B[4];
  #pragma unroll
  for (int b = 0; b < 4; ++b){
    const float* a = h + b*128;
    float t[16];
    #pragma unroll
    for (int l = 0; l < 16; ++l){
      float a0 = a[l]*a[l],       a4 = a[64+l]*a[64+l];
      float a1 = a[16+l]*a[16+l], a5 = a[80+l]*a[80+l];
      float a2 = a[32+l]*a[32+l], a6 = a[96+l]*a[96+l];
      float a3 = a[48+l]*a[48+l], a7 = a[112+l]*a[112+l];
      t[l] = ((a0+a4) + (a1+a5)) + ((a2+a6) + (a3+a7));
    }
    #pragma unroll
    for (int l = 0; l < 8; ++l) t[l] += t[l+8];
    #pragma unroll
    for (int l = 0; l < 4; ++l) t[l] += t[l+4];
    t[0] += t[2]; t[1] += t[3];
    B[b] = t[0] + t[1];
  }
  float total = (B[0]+B[1]) + (B[2]+B[3]);
  float nrm = sqrtf(total);
  nrm = fmaxf(nrm, 1e-12f);
  for (int k = 0; k < DD; ++k){
    float v = h[k] / nrm;
    h[k] = v;
    hb[k] = __float2bfloat16(v);
  }
}

// ---------------- bf16 MFMA S-prefilter, m97-style global_load_lds staging ----------------
__global__ void __launch_bounds__(256)
s_gemm_mfma(const unsigned short* embB, __hip_bfloat16* Sap, int row0){
  __shared__ unsigned short Asm[128*32];
  __shared__ unsigned short Bsm[128*32];
  const int tid = threadIdx.x;
  const int wave = tid >> 6, lane = tid & 63;
  const int wm = (wave & 1) * 64, wn = (wave >> 1) * 64;
  const int bm = blockIdx.y * 128, bn = blockIdx.x * 128;
  const int lm = lane & 15, kg = lane >> 4;
  const int ml = lane >> 2;
  const int clog = (lane & 3) ^ (ml & 3);
  const size_t gA0 = (size_t)(row0 + bm + 32*wave + ml)*DD + clog*8;
  const size_t gB0 = (size_t)(       bn + 32*wave + ml)*DD + clog*8;
  unsigned short* lA = &Asm[(32*wave)*32];
  unsigned short* lB = &Bsm[(32*wave)*32];
  f32x4 acc[4][4] = {};
  for (int k0 = 0; k0 < DD; k0 += 32){
    async_lds16(embB + gA0 + k0,          lA);
    async_lds16(embB + gA0 + 16*DD + k0,  lA + 16*32);
    async_lds16(embB + gB0 + k0,          lB);
    async_lds16(embB + gB0 + 16*DD + k0,  lB + 16*32);
    __syncthreads();
    bf16x8 af[4], bfr[4];
    #pragma unroll
    for (int i = 0; i < 4; ++i){
      int r = wm + i*16 + lm;
      af[i] = *(const bf16x8*)&Asm[r*32 + ((kg ^ (r&3))*8)];
    }
    #pragma unroll
    for (int j = 0; j < 4; ++j){
      int r = wn + j*16 + lm;
      bfr[j] = *(const bf16x8*)&Bsm[r*32 + ((kg ^ (r&3))*8)];
    }
    #pragma unroll
    for (int i = 0; i < 4; ++i)
      #pragma unroll
      for (int j = 0; j < 4; ++j)
        acc[i][j] = __builtin_amdgcn_mfma_f32_16x16x32_bf16(af[i], bfr[j], acc[i][j], 0, 0, 0);
    __syncthreads();
  }
  const int crow = kg * 4;
  #pragma unroll
  for (int i = 0; i < 4; ++i)
    #pragma unroll
    for (int j = 0; j < 4; ++j)
      #pragma unroll
      for (int r = 0; r < 4; ++r){
        int m = bm + wm + i*16 + crow + r;
        int n = bn + wn + j*16 + lm;
        Sap[(size_t)m*NN + n] = __float2bfloat16(acc[i][j][r]);
      }
}

// ---------------- candidate selection: 12-bit histogram + exact-key refinement ----------------
__global__ void __launch_bounds__(256)
cand_kernel(const __hip_bfloat16* Sap, int row0, int* cand, int* cand_cnt){
  __shared__ int hist[4096];
  __shared__ int partial[256];
  __shared__ int subhist[16];
  __shared__ int sh_T, sh_ST, sh_cab, sh_cnt;
  const int rl = blockIdx.x, tid = threadIdx.x;
  const unsigned short* srow = (const unsigned short*)Sap + (size_t)rl*NN;
  for (int b = tid; b < 4096; b += 256) hist[b] = 0;
  if (tid < 16) subhist[tid] = 0;
  if (tid == 0) sh_cnt = 0;
  __syncthreads();
  unsigned short uv[32];
  #pragma unroll
  for (int m = 0; m < 32; ++m){
    unsigned short u = srow[tid + (m<<8)];
    uv[m] = (unsigned short)(u ^ ((u & 0x8000u) ? 0xFFFFu : 0x8000u));  // order-preserving
    atomicAdd(&hist[uv[m] >> 4], 1);
  }
  __syncthreads();
  int ps = 0;
  #pragma unroll
  for (int b = 0; b < 16; ++b) ps += hist[tid*16 + b];
  partial[tid] = ps;
  __syncthreads();
  if (tid == 0){
    int c = 0, t = 255;
    for (; t > 0; --t){ if (c + partial[t] >= CTARGET) break; c += partial[t]; }
    int T = t*16;
    for (int b = 15; b >= 0; --b){
      int h = hist[t*16 + b];
      if (c + h >= CTARGET){ T = t*16 + b; break; }
      c += h;
    }
    sh_T = T; sh_cab = c;          // count strictly above bucket T
  }
  __syncthreads();
  const int T = sh_T;
  #pragma unroll
  for (int m = 0; m < 32; ++m)
    if ((uv[m] >> 4) == T) atomicAdd(&subhist[uv[m] & 15], 1);
  __syncthreads();
  if (tid == 0){
    int c = sh_cab, st = 0;
    for (int s2 = 15; s2 >= 0; --s2){ c += subhist[s2]; if (c >= CTARGET){ st = s2; break; } }
    sh_ST = st;
  }
  __syncthreads();
  const int ST = sh_ST;
  #pragma unroll
  for (int m = 0; m < 32; ++m){
    int hi = uv[m] >> 4;
    bool keep = (hi > T) || (hi == T && (uv[m] & 15) >= ST);
    if (keep){
      int pos = atomicAdd(&sh_cnt, 1);
      if (pos < CCAP) cand[(size_t)(row0+rl)*CCAP + pos] = tid + (m<<8);
    }
  }
  __syncthreads();
  if (tid == 0) cand_cnt[row0+rl] = (sh_cnt < CCAP) ? sh_cnt : CCAP;
}

// ---------------- exact fp32-chain rescore, j-bucketed for L2 residency ----------------
__global__ void __launch_bounds__(256)
rescore_pass(const float* emb, const int* cand, const int* cand_cnt, float* sval, int pass){
  __shared__ float ea[DD];
  const int row = blockIdx.x, tid = threadIdx.x;
  for (int k = tid; k < DD; k += 256) ea[k] = emb[(size_t)row*DD + k];
  const int cnt = cand_cnt[row];
  __syncthreads();
  for (int c = tid; c < cnt; c += 256){
    int j = cand[(size_t)row*CCAP + c];
    if ((j >> 11) != pass) continue;           // 4MB emb slice per pass
    const float4* eb = (const float4*)(emb + (size_t)j*DD);
    float acc = 0.f;
    #pragma unroll 8
    for (int k4 = 0; k4 < DD/4; ++k4){
      float4 v = eb[k4];
      acc = fmaf(ea[k4*4+0], v.x, acc);        // exact np chain, k ascending
      acc = fmaf(ea[k4*4+1], v.y, acc);
      acc = fmaf(ea[k4*4+2], v.z, acc);
      acc = fmaf(ea[k4*4+3], v.w, acc);
    }
    sval[(size_t)row*CCAP + c] = acc;
  }
}

// ---------------- final top-31: bitonic over 128 keys (value desc, index asc) ----------------
__global__ void __launch_bounds__(128)
select_topk(const float* sval, const int* cand, const int* cand_cnt, float* tv, int* ti){
  __shared__ unsigned long long keys[CCAP];
  const int row = blockIdx.x, tid = threadIdx.x;
  const int cnt = cand_cnt[row];
  unsigned long long key = 0ull;
  if (tid < cnt){
    int j = cand[(size_t)row*CCAP + tid];
    unsigned u = __float_as_uint(sval[(size_t)row*CCAP + tid]);
    u = (u & 0x80000000u) ? ~u : (u | 0x80000000u);
    key = ((unsigned long long)u << 32) | (unsigned long long)(0xFFFFFFFFu - (unsigned)j);
  }
  keys[tid] = key;
  __syncthreads();
  for (int kk = 2; kk <= CCAP; kk <<= 1){
    for (int jj = kk >> 1; jj > 0; jj >>= 1){
      int l = tid ^ jj;
      if (l > tid){
        unsigned long long a = keys[tid], b = keys[l];
        bool up = (tid & kk) == 0;             // descending
        if (up ? (a < b) : (a > b)){ keys[tid] = b; keys[l] = a; }
      }
      __syncthreads();
    }
  }
  if (tid < KK){
    unsigned long long k2 = keys[tid];
    unsigned u  = (unsigned)(k2 >> 32);
    unsigned uj = 0xFFFFFFFFu - (unsigned)(k2 & 0xFFFFFFFFull);
    unsigned fv = (u & 0x80000000u) ? (u ^ 0x80000000u) : ~u;
    tv[(size_t)row*KK + tid] = __uint_as_float(fv);
    ti[(size_t)row*KK + tid] = (int)uj;
  }
}

// ---------------- edge-list processing ----------------
__global__ void deg_count_kernel(const float* tv, const int* ti, double* deg, int* in_count){
  int e = blockIdx.x*256 + threadIdx.x;
  if (e >= NE) return;
  int i = e / KK;
  int j = ti[e];
  float s = tv[e]; if (s < 0.f) s = 0.f;
  double h = 0.5 * (double)s;
  atomicAdd(&deg[i], h);
  atomicAdd(&deg[j], h);
  atomicAdd(&in_count[j], 1);
}

// single block: dinv (parallel) + in_off exclusive scan
__global__ void scan_dinv_kernel(const int* in_count, int* in_off, const double* deg, double* dinv){
  __shared__ int part[256];
  const int tid = threadIdx.x;
  for (int i = tid; i < NN; i += 256) dinv[i] = 1.0 / (sqrt(deg[i]) + 1e-10);
  const int base = tid * 32;
  int local[32], sum = 0;
  for (int m = 0; m < 32; ++m){ local[m] = sum; sum += in_count[base + m]; }
  part[tid] = sum; __syncthreads();
  if (tid == 0){ int acc = 0; for (int t = 0; t < 256; ++t){ int p = part[t]; part[t] = acc; acc += p; } }
  __syncthreads();
  const int off = part[tid];
  for (int m = 0; m < 32; ++m) in_off[base + m] = off + local[m];
  if (tid == 255) in_off[NN] = NE;
}

__global__ void fill_kernel(const float* tv, const int* ti, const double* dinv,
                            const int* in_off, int* cursor, int* in_src, float* in_w, float* own_w){
  int e = blockIdx.x*256 + threadIdx.x;
  if (e >= NE) return;
  int i = e / KK;
  int j = ti[e];
  float s = tv[e]; if (s < 0.f) s = 0.f;
  float w = (float)(0.5 * (double)s * dinv[i] * dinv[j]);
  own_w[e] = w;
  int pos = atomicAdd(&cursor[j], 1);
  in_src[in_off[j] + pos] = i;
  in_w [in_off[j] + pos] = w;
}

// ---------------- dense adj: one block per row, LDS merge, vectorized stores ----------------
__global__ void dense_fill(const int* ti, const float* own_w, const int* in_off,
                           const int* in_src, const float* in_w,
                           void* outp, const int* flagp){
  __shared__ float row[NN];
  const int f = *flagp;
  const int i = blockIdx.x, tid = threadIdx.x;
  for (int c = tid*4; c < NN; c += 1024) *(float4*)&row[c] = make_float4(0.f,0.f,0.f,0.f);
  __syncthreads();
  if (tid < KK)
    atomicAdd(&row[ti[(size_t)i*KK + tid]], own_w[(size_t)i*KK + tid]);
  const int p1 = in_off[i+1];
  for (int p = in_off[i] + tid; p < p1; p += 256)
    atomicAdd(&row[in_src[p]], in_w[p]);
  __syncthreads();
  if (f){
    float* adj = (float*)outp + (size_t)NN*OO + (size_t)i*NN;
    for (int c = tid*4; c < NN; c += 1024) *(float4*)&adj[c] = *(float4*)&row[c];
  } else {
    __hip_bfloat16* adj = (__hip_bfloat16*)outp + (size_t)NN*OO + (size_t)i*NN;
    for (int c = tid*8; c < NN; c += 2048){
      unsigned u[8];
      #pragma unroll
      for (int q = 0; q < 8; ++q){
        __hip_bfloat16 b = __float2bfloat16(row[c+q]);
        u[q] = *(unsigned short*)&b;
      }
      uint4 o;
      o.x = u[0] | (u[1]<<16); o.y = u[2] | (u[3]<<16);
      o.z = u[4] | (u[5]<<16); o.w = u[6] | (u[7]<<16);
      *(uint4*)&adj[c] = o;
    }
  }
}

// ---------------- GCN tail ----------------
__global__ void spmm1_kernel(const float* xw0, const float* own_w, const int* ti,
                             const int* in_off, const int* in_src, const float* in_w, float* x1){
  const int i = blockIdx.x, c = threadIdx.x;
  float acc = 0.f;
  const int*   oi = ti    + (size_t)i*KK;
  const float* ow = own_w + (size_t)i*KK;
  for (int m = 0; m < KK; ++m)
    acc = fmaf(ow[m], xw0[(size_t)oi[m]*HH + c], acc);
  const int p0 = in_off[i], p1 = in_off[i+1];
  for (int p = p0; p < p1; ++p)
    acc = fmaf(in_w[p], xw0[(size_t)in_src[p]*HH + c], acc);
  x1[(size_t)i*HH + c] = acc > 0.f ? acc : 0.f;
}

__global__ void gemm_xw1(const float* x1, const void* W1, const void* b1,
                         float* xw1, const int* flagp){
  const int f = *flagp;
  __shared__ float xs[16][257];
  __shared__ float ws[16][257];
  const int tid = threadIdx.x;
  const int row0 = blockIdx.x * 16;
  for (int t = tid; t < 16*256; t += 256){
    int r = t >> 8, k = t & 255;
    xs[r][k] = x1[(size_t)(row0 + r)*HH + k];
    ws[r][k] = ldf(W1, (size_t)r*HH + k, f);
  }
  __syncthreads();
  const int r = tid >> 4, c = tid & 15;
  float a = 0.f;
  #pragma unroll 8
  for (int k = 0; k < HH; ++k) a = fmaf(xs[r][k], ws[c][k], a);
  xw1[(size_t)(row0 + r)*OO + c] = a + ldf(b1, c, f);
}

// 4 rows per 64-thread block: r = tid>>4, c = tid&15
__global__ void spmm2_kernel(const float* xw1, const float* own_w, const int* ti,
                             const int* in_off, const int* in_src, const float* in_w,
                             void* outp, const int* flagp){
  const int i = blockIdx.x*4 + (threadIdx.x >> 4);
  const int c = threadIdx.x & 15;
  const int f = *flagp;
  float acc = 0.f;
  const int*   oi = ti    + (size_t)i*KK;
  const float* ow = own_w + (size_t)i*KK;
  for (int m = 0; m < KK; ++m)
    acc = fmaf(ow[m], xw1[(size_t)oi[m]*OO + c], acc);
  const int p0 = in_off[i], p1 = in_off[i+1];
  for (int p = p0; p < p1; ++p)
    acc = fmaf(in_w[p], xw1[(size_t)in_src[p]*OO + c], acc);
  if (f) ((float*)outp)[(size_t)i*OO + c] = acc;
  else   ((__hip_bfloat16*)outp)[(size_t)i*OO + c] = __float2bfloat16(acc);
}

extern "C" void kernel_launch(void* const* d_in, const int* in_sizes, int n_in,
                              void* d_out, int out_size, void* d_ws, size_t ws_size,
                              hipStream_t stream) {
  (void)in_sizes; (void)n_in; (void)out_size; (void)ws_size;
  const void* features = d_in[0];
  const void* x        = d_in[1];
  const void* gsl_W0   = d_in[2];
  const void* gsl_b0   = d_in[3];
  const void* gsl_W1   = d_in[4];
  const void* gsl_b1   = d_in[5];
  const void* gcn_W0   = d_in[6];
  const void* gcn_b0   = d_in[7];
  const void* gcn_W1   = d_in[8];
  const void* gcn_b1   = d_in[9];

  // Big scratch inside the adj half of d_out (fully rewritten by dense_fill at the end).
  char* base = (char*)d_out + ((size_t)512 << 10);
  float*          h1    = (float*)(base);                               // 16MB, dead after mlp2
  float*          emb   = (float*)(base + ((size_t)16 << 20));          // 16MB, dead after rescore
  __hip_bfloat16* embbf = (__hip_bfloat16*)(base + ((size_t)32 << 20)); // 8MB
  __hip_bfloat16* Sap   = (__hip_bfloat16*)(base + ((size_t)40 << 20)); // 32MB (per 2048-row batch)
  float*          tv    = (float*)(base + ((size_t)72 << 20));          // 1MB, dead after fill
  int*            cand  = (int*)  (base + ((size_t)73 << 20));          // 4MB (8192x128)
  float*          sval  = (float*)(base + ((size_t)77 << 20));          // 4MB
  int*            ccnt  = (int*)  (base + ((size_t)81 << 20));          // 32KB
  char*           misc  =          base + ((size_t)82 << 20);
  double* deg      = (double*)(misc);
  double* dinv     = (double*)(misc + 0x10000);
  int*    in_count = (int*)   (misc + 0x20000);
  int*    cursor   = (int*)   (misc + 0x28000);
  float*  xw0 = (float*)(base);                       // 8MB  (reuses h1, after rescore)
  float*  x1  = (float*)(base + ((size_t)8  << 20));  // 8MB
  float*  xw1 = (float*)(base + ((size_t)16 << 20));  // 0.5MB (reuses emb, dead by then)

  // d_ws (~4.096MB): arrays surviving until dense_fill, + flag
  char* sm = (char*)d_ws;
  int*   ti     = (int*)sm;    sm += (size_t)4*NE;
  float* own_w  = (float*)sm;  sm += (size_t)4*NE;
  int*   in_src = (int*)sm;    sm += (size_t)4*NE;
  float* in_w   = (float*)sm;  sm += (size_t)4*NE;
  int*   in_off = (int*)sm;    sm += (size_t)4*(NN+1);
  int*   flagp  = (int*)sm;    sm += 4;

  init_kernel<<<dim3(33), dim3(256), 0, stream>>>(features, flagp, deg, in_count, cursor);

  // GSL MLP — emulated numpy float32 semantics (ascending-FMA chains)
  gemm_nt_f32<true,  true,  DD><<<dim3(4,64), dim3(256), 0, stream>>>(features, gsl_W0, gsl_b0, h1,  flagp);
  gemm_nt_f32<false, false, DD><<<dim3(4,64), dim3(256), 0, stream>>>(h1,       gsl_W1, gsl_b1, emb, flagp);
  norm_np_kernel<<<dim3(32), dim3(256), 0, stream>>>(emb, embbf);

  // bf16-MFMA prefilter + candidate selection, batched (2048 rows / batch)
  for (int b = 0; b < NN/SBATCH; ++b){
    const int row0 = b * SBATCH;
    s_gemm_mfma<<<dim3(NN/128, SBATCH/128), dim3(256), 0, stream>>>((const unsigned short*)embbf, Sap, row0);
    cand_kernel<<<dim3(SBATCH), dim3(256), 0, stream>>>(Sap, row0, cand, ccnt);
  }
  // exact rescore (4 L2-resident passes) + final selection
  for (int p = 0; p < 4; ++p)
    rescore_pass<<<dim3(NN), dim3(256), 0, stream>>>(emb, cand, ccnt, sval, p);
  select_topk<<<dim3(NN), dim3(128), 0, stream>>>(sval, cand, ccnt, tv, ti);

  // graph assembly
  const int eb = (NE + 255)/256;
  deg_count_kernel<<<dim3(eb), dim3(256), 0, stream>>>(tv, ti, deg, in_count);
  scan_dinv_kernel<<<dim3(1), dim3(256), 0, stream>>>(in_count, in_off, deg, dinv);
  fill_kernel<<<dim3(eb), dim3(256), 0, stream>>>(tv, ti, dinv, in_off, cursor, in_src, in_w, own_w);

  // GCN (fp32, sparse adj) — writes outx
  gemm_nt_f32<true, false, HH><<<dim3(2,64), dim3(256), 0, stream>>>(x, gcn_W0, gcn_b0, xw0, flagp);
  spmm1_kernel<<<dim3(NN), dim3(256), 0, stream>>>(xw0, own_w, ti, in_off, in_src, in_w, x1);
  gemm_xw1<<<dim3(NN/16), dim3(256), 0, stream>>>(x1, gcn_W1, gcn_b1, xw1, flagp);
  spmm2_kernel<<<dim3(NN/4), dim3(64), 0, stream>>>(xw1, own_w, ti, in_off, in_src, in_w, d_out, flagp);

  // dense adj last: reads only d_ws
  dense_fill<<<dim3(NN), dim3(256), 0, stream>>>(ti, own_w, in_off, in_src, in_w, d_out, flagp);
}

// Round 10
// 1557.012 us; speedup vs baseline: 1.1646x; 1.1646x over previous
//
#include <hip/hip_runtime.h>
#include <hip/hip_bf16.h>
#include <stdint.h>

#define NN 8192
#define DD 512
#define KK 31
#define HH 256
#define OO 16
#define SBATCH 2048
#define NE (NN*KK)    // 253952 directed edges
#define CTARGET 64
#define CCAP 128

typedef __attribute__((ext_vector_type(8))) short bf16x8;
typedef __attribute__((ext_vector_type(4))) float f32x4;

__device__ __forceinline__ float bf2f(__hip_bfloat16 v){ return __bfloat162float(v); }

__device__ __forceinline__ void async_lds16(const void* g, void* l){
  __builtin_amdgcn_global_load_lds((const __attribute__((address_space(1))) unsigned int*)g,
                                   (__attribute__((address_space(3))) unsigned int*)l, 16, 0, 0);
}

// runtime input-dtype flag: 1 = inputs are float32, 0 = inputs are bf16
__device__ __forceinline__ float ldf(const void* p, size_t i, int f){
  return f ? ((const float*)p)[i] : bf2f(((const __hip_bfloat16*)p)[i]);
}

// block 0: dtype-detect -> flag ; blocks 1..32: zero deg/in_count/cursor
__global__ void init_kernel(const void* feat, int* flag, double* deg, int* in_count, int* cursor){
  const int tid = threadIdx.x;
  if (blockIdx.x == 0){
    __shared__ int red[256];
    int cnt = 0;
    const __hip_bfloat16* fb = (const __hip_bfloat16*)feat;
    for (int m = 0; m < 16; ++m){
      float v = bf2f(fb[tid*16 + m]);
      if (!(fabsf(v) <= 100.f)) cnt++;
    }
    red[tid] = cnt; __syncthreads();
    for (int s = 128; s > 0; s >>= 1){ if (tid < s) red[tid] += red[tid+s]; __syncthreads(); }
    if (tid == 0) *flag = (red[0] > 40) ? 1 : 0;
  } else {
    int i = (blockIdx.x - 1)*256 + tid;
    if (i < NN){ deg[i] = 0.0; in_count[i] = 0; cursor[i] = 0; }
  }
}

// ---------------- fp32 NT GEMM, np/BLAS-exact chain; 128x128 tile, 8x8/thread ----------------
// C[M][OUTW] = A[M][512] @ W[OUTW][512]^T + b ; per-C-element single fp32 acc, k ascending.
template<bool A_RAW, bool RELU, int OUTW>
__global__ void __launch_bounds__(256)
gemm_nt_f32(const void* Ap, const void* W, const void* bias, float* C, const int* flagp){
  const int f = *flagp;
  __shared__ float As[16*132];   // [k][m] transposed
  __shared__ float Bs[16*132];   // [k][n]
  const int tid = threadIdx.x;
  const int tx = tid & 15, ty = tid >> 4;
  const int bm = blockIdx.y*128, bn = blockIdx.x*128;
  float acc[8][8] = {};
  for (int k0 = 0; k0 < DD; k0 += 16){
    #pragma unroll
    for (int p = 0; p < 2; ++p){
      int chunk = p*256 + tid;        // 0..511
      int m = chunk >> 2, c = chunk & 3;
      float v0,v1,v2,v3;
      if (A_RAW){
        size_t o = (size_t)(bm+m)*DD + k0 + c*4;
        v0=ldf(Ap,o,f); v1=ldf(Ap,o+1,f); v2=ldf(Ap,o+2,f); v3=ldf(Ap,o+3,f);
      } else {
        const float* a = (const float*)Ap + (size_t)(bm+m)*DD + k0 + c*4;
        v0=a[0]; v1=a[1]; v2=a[2]; v3=a[3];
      }
      As[(c*4+0)*132+m]=v0; As[(c*4+1)*132+m]=v1; As[(c*4+2)*132+m]=v2; As[(c*4+3)*132+m]=v3;
      size_t ow = (size_t)(bn+m)*DD + k0 + c*4;
      Bs[(c*4+0)*132+m]=ldf(W,ow,f);   Bs[(c*4+1)*132+m]=ldf(W,ow+1,f);
      Bs[(c*4+2)*132+m]=ldf(W,ow+2,f); Bs[(c*4+3)*132+m]=ldf(W,ow+3,f);
    }
    __syncthreads();
    #pragma unroll
    for (int kk = 0; kk < 16; ++kk){
      const float4* Av = (const float4*)&As[kk*132 + ty*8];
      const float4* Bv = (const float4*)&Bs[kk*132 + tx*8];
      float4 a0 = Av[0], a1 = Av[1], b0 = Bv[0], b1 = Bv[1];
      float a[8] = {a0.x,a0.y,a0.z,a0.w,a1.x,a1.y,a1.z,a1.w};
      float b[8] = {b0.x,b0.y,b0.z,b0.w,b1.x,b1.y,b1.z,b1.w};
      #pragma unroll
      for (int i = 0; i < 8; ++i)
        #pragma unroll
        for (int j = 0; j < 8; ++j)
          acc[i][j] = fmaf(a[i], b[j], acc[i][j]);
    }
    __syncthreads();
  }
  #pragma unroll
  for (int i = 0; i < 8; ++i)
    #pragma unroll
    for (int j = 0; j < 8; ++j){
      int m = bm + ty*8 + i, n = bn + tx*8 + j;
      float v = acc[i][j] + ldf(bias, n, f);
      if (RELU && v < 0.f) v = 0.f;
      C[(size_t)m*OUTW + n] = v;
    }
}

// ---------------- np.linalg.norm emulation — one WAVE per row, bit-exact tree ----------------
// lane = 16*b + l : computes t[l] of 128-chunk b with the numpy/AVX512 square-add tree;
// shfl-down halving reproduces _mm512_reduce_add_ps pair order exactly.
__global__ void __launch_bounds__(256)
norm_np_kernel(float* emb, __hip_bfloat16* embbf){
  const int wave = threadIdx.x >> 6, lane = threadIdx.x & 63;
  const int row = blockIdx.x*4 + wave;
  float* h = emb + (size_t)row*DD;
  __hip_bfloat16* hb = embbf + (size_t)row*DD;
  const int b = lane >> 4, l = lane & 15;
  const float* a = h + b*128;
  float s0 = a[l]      * a[l],       s4 = a[64+l]  * a[64+l];
  float s1 = a[16+l]   * a[16+l],    s5 = a[80+l]  * a[80+l];
  float s2 = a[32+l]   * a[32+l],    s6 = a[96+l]  * a[96+l];
  float s3 = a[48+l]   * a[48+l],    s7 = a[112+l] * a[112+l];
  float t = ((s0+s4) + (s1+s5)) + ((s2+s6) + (s3+s7));
  t += __shfl_down(t, 8);
  t += __shfl_down(t, 4);
  t += __shfl_down(t, 2);
  t += __shfl_down(t, 1);          // lane 16b now holds B[b]
  float B0 = __shfl(t, 0), B1 = __shfl(t, 16), B2 = __shfl(t, 32), B3 = __shfl(t, 48);
  float total = (B0+B1) + (B2+B3);
  float nrm = fmaxf(sqrtf(total), 1e-12f);
  for (int k = lane; k < DD; k += 64){
    float v = h[k] / nrm;
    h[k] = v;
    hb[k] = __float2bfloat16(v);
  }
}

// ---------------- bf16 MFMA S-prefilter, m97-style global_load_lds staging ----------------
__global__ void __launch_bounds__(256)
s_gemm_mfma(const unsigned short* embB, __hip_bfloat16* Sap, int row0){
  __shared__ unsigned short Asm[128*32];
  __shared__ unsigned short Bsm[128*32];
  const int tid = threadIdx.x;
  const int wave = tid >> 6, lane = tid & 63;
  const int wm = (wave & 1) * 64, wn = (wave >> 1) * 64;
  const int bm = blockIdx.y * 128, bn = blockIdx.x * 128;
  const int lm = lane & 15, kg = lane >> 4;
  const int ml = lane >> 2;
  const int clog = (lane & 3) ^ (ml & 3);
  const size_t gA0 = (size_t)(row0 + bm + 32*wave + ml)*DD + clog*8;
  const size_t gB0 = (size_t)(       bn + 32*wave + ml)*DD + clog*8;
  unsigned short* lA = &Asm[(32*wave)*32];
  unsigned short* lB = &Bsm[(32*wave)*32];
  f32x4 acc[4][4] = {};
  for (int k0 = 0; k0 < DD; k0 += 32){
    async_lds16(embB + gA0 + k0,          lA);
    async_lds16(embB + gA0 + 16*DD + k0,  lA + 16*32);
    async_lds16(embB + gB0 + k0,          lB);
    async_lds16(embB + gB0 + 16*DD + k0,  lB + 16*32);
    __syncthreads();
    bf16x8 af[4], bfr[4];
    #pragma unroll
    for (int i = 0; i < 4; ++i){
      int r = wm + i*16 + lm;
      af[i] = *(const bf16x8*)&Asm[r*32 + ((kg ^ (r&3))*8)];
    }
    #pragma unroll
    for (int j = 0; j < 4; ++j){
      int r = wn + j*16 + lm;
      bfr[j] = *(const bf16x8*)&Bsm[r*32 + ((kg ^ (r&3))*8)];
    }
    #pragma unroll
    for (int i = 0; i < 4; ++i)
      #pragma unroll
      for (int j = 0; j < 4; ++j)
        acc[i][j] = __builtin_amdgcn_mfma_f32_16x16x32_bf16(af[i], bfr[j], acc[i][j], 0, 0, 0);
    __syncthreads();
  }
  const int crow = kg * 4;
  #pragma unroll
  for (int i = 0; i < 4; ++i)
    #pragma unroll
    for (int j = 0; j < 4; ++j)
      #pragma unroll
      for (int r = 0; r < 4; ++r){
        int m = bm + wm + i*16 + crow + r;
        int n = bn + wn + j*16 + lm;
        Sap[(size_t)m*NN + n] = __float2bfloat16(acc[i][j][r]);
      }
}

// ---------------- candidate selection: 12-bit histogram + exact-key refinement ----------------
__global__ void __launch_bounds__(256)
cand_kernel(const __hip_bfloat16* Sap, int row0, int* cand, int* cand_cnt){
  __shared__ int hist[4096];
  __shared__ int partial[256];
  __shared__ int subhist[16];
  __shared__ int sh_T, sh_ST, sh_cab, sh_cnt;
  const int rl = blockIdx.x, tid = threadIdx.x;
  const unsigned short* srow = (const unsigned short*)Sap + (size_t)rl*NN;
  for (int b = tid; b < 4096; b += 256) hist[b] = 0;
  if (tid < 16) subhist[tid] = 0;
  if (tid == 0) sh_cnt = 0;
  __syncthreads();
  unsigned short uv[32];
  #pragma unroll
  for (int m = 0; m < 32; ++m){
    unsigned short u = srow[tid + (m<<8)];
    uv[m] = (unsigned short)(u ^ ((u & 0x8000u) ? 0xFFFFu : 0x8000u));  // order-preserving
    atomicAdd(&hist[uv[m] >> 4], 1);
  }
  __syncthreads();
  int ps = 0;
  #pragma unroll
  for (int b = 0; b < 16; ++b) ps += hist[tid*16 + b];
  partial[tid] = ps;
  __syncthreads();
  if (tid == 0){
    int c = 0, t = 255;
    for (; t > 0; --t){ if (c + partial[t] >= CTARGET) break; c += partial[t]; }
    int T = t*16;
    for (int b = 15; b >= 0; --b){
      int h = hist[t*16 + b];
      if (c + h >= CTARGET){ T = t*16 + b; break; }
      c += h;
    }
    sh_T = T; sh_cab = c;          // count strictly above bucket T
  }
  __syncthreads();
  const int T = sh_T;
  #pragma unroll
  for (int m = 0; m < 32; ++m)
    if ((uv[m] >> 4) == T) atomicAdd(&subhist[uv[m] & 15], 1);
  __syncthreads();
  if (tid == 0){
    int c = sh_cab, st = 0;
    for (int s2 = 15; s2 >= 0; --s2){ c += subhist[s2]; if (c >= CTARGET){ st = s2; break; } }
    sh_ST = st;
  }
  __syncthreads();
  const int ST = sh_ST;
  #pragma unroll
  for (int m = 0; m < 32; ++m){
    int hi = uv[m] >> 4;
    bool keep = (hi > T) || (hi == T && (uv[m] & 15) >= ST);
    if (keep){
      int pos = atomicAdd(&sh_cnt, 1);
      if (pos < CCAP) cand[(size_t)(row0+rl)*CCAP + pos] = tid + (m<<8);
    }
  }
  __syncthreads();
  if (tid == 0) cand_cnt[row0+rl] = (sh_cnt < CCAP) ? sh_cnt : CCAP;
}

// ---------------- exact fp32-chain rescore, j-bucketed for L2 residency ----------------
__global__ void __launch_bounds__(256)
rescore_pass(const float* emb, const int* cand, const int* cand_cnt, float* sval, int pass){
  __shared__ float ea[DD];
  const int row = blockIdx.x, tid = threadIdx.x;
  for (int k = tid; k < DD; k += 256) ea[k] = emb[(size_t)row*DD + k];
  const int cnt = cand_cnt[row];
  __syncthreads();
  for (int c = tid; c < cnt; c += 256){
    int j = cand[(size_t)row*CCAP + c];
    if ((j >> 11) != pass) continue;           // 4MB emb slice per pass
    const float4* eb = (const float4*)(emb + (size_t)j*DD);
    float acc = 0.f;
    #pragma unroll 8
    for (int k4 = 0; k4 < DD/4; ++k4){
      float4 v = eb[k4];
      acc = fmaf(ea[k4*4+0], v.x, acc);        // exact np chain, k ascending
      acc = fmaf(ea[k4*4+1], v.y, acc);
      acc = fmaf(ea[k4*4+2], v.z, acc);
      acc = fmaf(ea[k4*4+3], v.w, acc);
    }
    sval[(size_t)row*CCAP + c] = acc;
  }
}

// ---------------- final top-31: bitonic over 128 keys (value desc, index asc) ----------------
__global__ void __launch_bounds__(128)
select_topk(const float* sval, const int* cand, const int* cand_cnt, float* tv, int* ti){
  __shared__ unsigned long long keys[CCAP];
  const int row = blockIdx.x, tid = threadIdx.x;
  const int cnt = cand_cnt[row];
  unsigned long long key = 0ull;
  if (tid < cnt){
    int j = cand[(size_t)row*CCAP + tid];
    unsigned u = __float_as_uint(sval[(size_t)row*CCAP + tid]);
    u = (u & 0x80000000u) ? ~u : (u | 0x80000000u);
    key = ((unsigned long long)u << 32) | (unsigned long long)(0xFFFFFFFFu - (unsigned)j);
  }
  keys[tid] = key;
  __syncthreads();
  for (int kk = 2; kk <= CCAP; kk <<= 1){
    for (int jj = kk >> 1; jj > 0; jj >>= 1){
      int l = tid ^ jj;
      if (l > tid){
        unsigned long long a = keys[tid], b = keys[l];
        bool up = (tid & kk) == 0;             // descending
        if (up ? (a < b) : (a > b)){ keys[tid] = b; keys[l] = a; }
      }
      __syncthreads();
    }
  }
  if (tid < KK){
    unsigned long long k2 = keys[tid];
    unsigned u  = (unsigned)(k2 >> 32);
    unsigned uj = 0xFFFFFFFFu - (unsigned)(k2 & 0xFFFFFFFFull);
    unsigned fv = (u & 0x80000000u) ? (u ^ 0x80000000u) : ~u;
    tv[(size_t)row*KK + tid] = __uint_as_float(fv);
    ti[(size_t)row*KK + tid] = (int)uj;
  }
}

// ---------------- edge-list processing ----------------
__global__ void deg_count_kernel(const float* tv, const int* ti, double* deg, int* in_count){
  int e = blockIdx.x*256 + threadIdx.x;
  if (e >= NE) return;
  int i = e / KK;
  int j = ti[e];
  float s = tv[e]; if (s < 0.f) s = 0.f;
  double h = 0.5 * (double)s;
  atomicAdd(&deg[i], h);
  atomicAdd(&deg[j], h);
  atomicAdd(&in_count[j], 1);
}

// single block: dinv (parallel) + in_off exclusive scan
__global__ void scan_dinv_kernel(const int* in_count, int* in_off, const double* deg, double* dinv){
  __shared__ int part[256];
  const int tid = threadIdx.x;
  for (int i = tid; i < NN; i += 256) dinv[i] = 1.0 / (sqrt(deg[i]) + 1e-10);
  const int base = tid * 32;
  int local[32], sum = 0;
  for (int m = 0; m < 32; ++m){ local[m] = sum; sum += in_count[base + m]; }
  part[tid] = sum; __syncthreads();
  if (tid == 0){ int acc = 0; for (int t = 0; t < 256; ++t){ int p = part[t]; part[t] = acc; acc += p; } }
  __syncthreads();
  const int off = part[tid];
  for (int m = 0; m < 32; ++m) in_off[base + m] = off + local[m];
  if (tid == 255) in_off[NN] = NE;
}

__global__ void fill_kernel(const float* tv, const int* ti, const double* dinv,
                            const int* in_off, int* cursor, int* in_src, float* in_w, float* own_w){
  int e = blockIdx.x*256 + threadIdx.x;
  if (e >= NE) return;
  int i = e / KK;
  int j = ti[e];
  float s = tv[e]; if (s < 0.f) s = 0.f;
  float w = (float)(0.5 * (double)s * dinv[i] * dinv[j]);
  own_w[e] = w;
  int pos = atomicAdd(&cursor[j], 1);
  in_src[in_off[j] + pos] = i;
  in_w [in_off[j] + pos] = w;
}

// ---------------- dense adj: one block per row, LDS merge, vectorized stores ----------------
__global__ void dense_fill(const int* ti, const float* own_w, const int* in_off,
                           const int* in_src, const float* in_w,
                           void* outp, const int* flagp){
  __shared__ float row[NN];
  const int f = *flagp;
  const int i = blockIdx.x, tid = threadIdx.x;
  for (int c = tid*4; c < NN; c += 1024) *(float4*)&row[c] = make_float4(0.f,0.f,0.f,0.f);
  __syncthreads();
  if (tid < KK)
    atomicAdd(&row[ti[(size_t)i*KK + tid]], own_w[(size_t)i*KK + tid]);
  const int p1 = in_off[i+1];
  for (int p = in_off[i] + tid; p < p1; p += 256)
    atomicAdd(&row[in_src[p]], in_w[p]);
  __syncthreads();
  if (f){
    float* adj = (float*)outp + (size_t)NN*OO + (size_t)i*NN;
    for (int c = tid*4; c < NN; c += 1024) *(float4*)&adj[c] = *(float4*)&row[c];
  } else {
    __hip_bfloat16* adj = (__hip_bfloat16*)outp + (size_t)NN*OO + (size_t)i*NN;
    for (int c = tid*8; c < NN; c += 2048){
      unsigned u[8];
      #pragma unroll
      for (int q = 0; q < 8; ++q){
        __hip_bfloat16 b = __float2bfloat16(row[c+q]);
        u[q] = *(unsigned short*)&b;
      }
      uint4 o;
      o.x = u[0] | (u[1]<<16); o.y = u[2] | (u[3]<<16);
      o.z = u[4] | (u[5]<<16); o.w = u[6] | (u[7]<<16);
      *(uint4*)&adj[c] = o;
    }
  }
}

// ---------------- GCN tail ----------------
__global__ void spmm1_kernel(const float* xw0, const float* own_w, const int* ti,
                             const int* in_off, const int* in_src, const float* in_w, float* x1){
  const int i = blockIdx.x, c = threadIdx.x;
  float acc = 0.f;
  const int*   oi = ti    + (size_t)i*KK;
  const float* ow = own_w + (size_t)i*KK;
  for (int m = 0; m < KK; ++m)
    acc = fmaf(ow[m], xw0[(size_t)oi[m]*HH + c], acc);
  const int p0 = in_off[i], p1 = in_off[i+1];
  for (int p = p0; p < p1; ++p)
    acc = fmaf(in_w[p], xw0[(size_t)in_src[p]*HH + c], acc);
  x1[(size_t)i*HH + c] = acc > 0.f ? acc : 0.f;
}

__global__ void gemm_xw1(const float* x1, const void* W1, const void* b1,
                         float* xw1, const int* flagp){
  const int f = *flagp;
  __shared__ float xs[16][257];
  __shared__ float ws[16][257];
  const int tid = threadIdx.x;
  const int row0 = blockIdx.x * 16;
  for (int t = tid; t < 16*256; t += 256){
    int r = t >> 8, k = t & 255;
    xs[r][k] = x1[(size_t)(row0 + r)*HH + k];
    ws[r][k] = ldf(W1, (size_t)r*HH + k, f);
  }
  __syncthreads();
  const int r = tid >> 4, c = tid & 15;
  float a = 0.f;
  #pragma unroll 8
  for (int k = 0; k < HH; ++k) a = fmaf(xs[r][k], ws[c][k], a);
  xw1[(size_t)(row0 + r)*OO + c] = a + ldf(b1, c, f);
}

// 4 rows per 64-thread block: r = tid>>4, c = tid&15
__global__ void spmm2_kernel(const float* xw1, const float* own_w, const int* ti,
                             const int* in_off, const int* in_src, const float* in_w,
                             void* outp, const int* flagp){
  const int i = blockIdx.x*4 + (threadIdx.x >> 4);
  const int c = threadIdx.x & 15;
  const int f = *flagp;
  float acc = 0.f;
  const int*   oi = ti    + (size_t)i*KK;
  const float* ow = own_w + (size_t)i*KK;
  for (int m = 0; m < KK; ++m)
    acc = fmaf(ow[m], xw1[(size_t)oi[m]*OO + c], acc);
  const int p0 = in_off[i], p1 = in_off[i+1];
  for (int p = p0; p < p1; ++p)
    acc = fmaf(in_w[p], xw1[(size_t)in_src[p]*OO + c], acc);
  if (f) ((float*)outp)[(size_t)i*OO + c] = acc;
  else   ((__hip_bfloat16*)outp)[(size_t)i*OO + c] = __float2bfloat16(acc);
}

extern "C" void kernel_launch(void* const* d_in, const int* in_sizes, int n_in,
                              void* d_out, int out_size, void* d_ws, size_t ws_size,
                              hipStream_t stream) {
  (void)in_sizes; (void)n_in; (void)out_size; (void)ws_size;
  const void* features = d_in[0];
  const void* x        = d_in[1];
  const void* gsl_W0   = d_in[2];
  const void* gsl_b0   = d_in[3];
  const void* gsl_W1   = d_in[4];
  const void* gsl_b1   = d_in[5];
  const void* gcn_W0   = d_in[6];
  const void* gcn_b0   = d_in[7];
  const void* gcn_W1   = d_in[8];
  const void* gcn_b1   = d_in[9];

  // Big scratch inside the adj half of d_out (fully rewritten by dense_fill at the end).
  char* base = (char*)d_out + ((size_t)512 << 10);
  float*          h1    = (float*)(base);                               // 16MB, dead after mlp2
  float*          emb   = (float*)(base + ((size_t)16 << 20));          // 16MB, dead after rescore
  __hip_bfloat16* embbf = (__hip_bfloat16*)(base + ((size_t)32 << 20)); // 8MB
  __hip_bfloat16* Sap   = (__hip_bfloat16*)(base + ((size_t)40 << 20)); // 32MB (per 2048-row batch)
  float*          tv    = (float*)(base + ((size_t)72 << 20));          // 1MB, dead after fill
  int*            cand  = (int*)  (base + ((size_t)73 << 20));          // 4MB (8192x128)
  float*          sval  = (float*)(base + ((size_t)77 << 20));          // 4MB
  int*            ccnt  = (int*)  (base + ((size_t)81 << 20));          // 32KB
  char*           misc  =          base + ((size_t)82 << 20);
  double* deg      = (double*)(misc);
  double* dinv     = (double*)(misc + 0x10000);
  int*    in_count = (int*)   (misc + 0x20000);
  int*    cursor   = (int*)   (misc + 0x28000);
  float*  xw0 = (float*)(base);                       // 8MB  (reuses h1, after rescore)
  float*  x1  = (float*)(base + ((size_t)8  << 20));  // 8MB
  float*  xw1 = (float*)(base + ((size_t)16 << 20));  // 0.5MB (reuses emb, dead by then)

  // d_ws (~4.096MB): arrays surviving until dense_fill, + flag
  char* sm = (char*)d_ws;
  int*   ti     = (int*)sm;    sm += (size_t)4*NE;
  float* own_w  = (float*)sm;  sm += (size_t)4*NE;
  int*   in_src = (int*)sm;    sm += (size_t)4*NE;
  float* in_w   = (float*)sm;  sm += (size_t)4*NE;
  int*   in_off = (int*)sm;    sm += (size_t)4*(NN+1);
  int*   flagp  = (int*)sm;    sm += 4;

  init_kernel<<<dim3(33), dim3(256), 0, stream>>>(features, flagp, deg, in_count, cursor);

  // GSL MLP — emulated numpy float32 semantics (ascending-FMA chains)
  gemm_nt_f32<true,  true,  DD><<<dim3(4,64), dim3(256), 0, stream>>>(features, gsl_W0, gsl_b0, h1,  flagp);
  gemm_nt_f32<false, false, DD><<<dim3(4,64), dim3(256), 0, stream>>>(h1,       gsl_W1, gsl_b1, emb, flagp);
  norm_np_kernel<<<dim3(NN/4), dim3(256), 0, stream>>>(emb, embbf);

  // bf16-MFMA prefilter + candidate selection, batched (2048 rows / batch)
  for (int b = 0; b < NN/SBATCH; ++b){
    const int row0 = b * SBATCH;
    s_gemm_mfma<<<dim3(NN/128, SBATCH/128), dim3(256), 0, stream>>>((const unsigned short*)embbf, Sap, row0);
    cand_kernel<<<dim3(SBATCH), dim3(256), 0, stream>>>(Sap, row0, cand, ccnt);
  }
  // exact rescore (4 L2-resident passes) + final selection
  for (int p = 0; p < 4; ++p)
    rescore_pass<<<dim3(NN), dim3(256), 0, stream>>>(emb, cand, ccnt, sval, p);
  select_topk<<<dim3(NN), dim3(128), 0, stream>>>(sval, cand, ccnt, tv, ti);

  // graph assembly
  const int eb = (NE + 255)/256;
  deg_count_kernel<<<dim3(eb), dim3(256), 0, stream>>>(tv, ti, deg, in_count);
  scan_dinv_kernel<<<dim3(1), dim3(256), 0, stream>>>(in_count, in_off, deg, dinv);
  fill_kernel<<<dim3(eb), dim3(256), 0, stream>>>(tv, ti, dinv, in_off, cursor, in_src, in_w, own_w);

  // GCN (fp32, sparse adj) — writes outx
  gemm_nt_f32<true, false, HH><<<dim3(2,64), dim3(256), 0, stream>>>(x, gcn_W0, gcn_b0, xw0, flagp);
  spmm1_kernel<<<dim3(NN), dim3(256), 0, stream>>>(xw0, own_w, ti, in_off, in_src, in_w, x1);
  gemm_xw1<<<dim3(NN/16), dim3(256), 0, stream>>>(x1, gcn_W1, gcn_b1, xw1, flagp);
  spmm2_kernel<<<dim3(NN/4), dim3(64), 0, stream>>>(xw1, own_w, ti, in_off, in_src, in_w, d_out, flagp);

  // dense adj last: reads only d_ws
  dense_fill<<<dim3(NN), dim3(256), 0, stream>>>(ti, own_w, in_off, in_src, in_w, d_out, flagp);
}

// Round 11
// 1500.419 us; speedup vs baseline: 1.2085x; 1.0377x over previous
//
#include <hip/hip_runtime.h>
#include <hip/hip_bf16.h>
#include <stdint.h>

#define NN 8192
#define DD 512
#define KK 31
#define HH 256
#define OO 16
#define SBATCH 4096
#define NE (NN*KK)    // 253952 directed edges
#define CTARGET 64
#define CCAP 128

typedef __attribute__((ext_vector_type(8))) short bf16x8;
typedef __attribute__((ext_vector_type(4))) float f32x4;
typedef __attribute__((ext_vector_type(8))) unsigned short u16x8;

__device__ __forceinline__ float bf2f(__hip_bfloat16 v){ return __bfloat162float(v); }

__device__ __forceinline__ void async_lds16(const void* g, void* l){
  __builtin_amdgcn_global_load_lds((const __attribute__((address_space(1))) unsigned int*)g,
                                   (__attribute__((address_space(3))) unsigned int*)l, 16, 0, 0);
}

// runtime input-dtype flag: 1 = inputs are float32, 0 = inputs are bf16
__device__ __forceinline__ float ldf(const void* p, size_t i, int f){
  return f ? ((const float*)p)[i] : bf2f(((const __hip_bfloat16*)p)[i]);
}

// block 0: dtype-detect -> flag ; blocks 1..32: zero deg/in_count/cursor
__global__ void init_kernel(const void* feat, int* flag, double* deg, int* in_count, int* cursor){
  const int tid = threadIdx.x;
  if (blockIdx.x == 0){
    __shared__ int red[256];
    int cnt = 0;
    const __hip_bfloat16* fb = (const __hip_bfloat16*)feat;
    for (int m = 0; m < 16; ++m){
      float v = bf2f(fb[tid*16 + m]);
      if (!(fabsf(v) <= 100.f)) cnt++;
    }
    red[tid] = cnt; __syncthreads();
    for (int s = 128; s > 0; s >>= 1){ if (tid < s) red[tid] += red[tid+s]; __syncthreads(); }
    if (tid == 0) *flag = (red[0] > 40) ? 1 : 0;
  } else {
    int i = (blockIdx.x - 1)*256 + tid;
    if (i < NN){ deg[i] = 0.0; in_count[i] = 0; cursor[i] = 0; }
  }
}

// ---------------- fp32 NT GEMM, np/BLAS-exact chain; 128x128 tile, 8x8/thread ----------------
template<bool A_RAW, bool RELU, int OUTW>
__global__ void __launch_bounds__(256)
gemm_nt_f32(const void* Ap, const void* W, const void* bias, float* C, const int* flagp){
  const int f = *flagp;
  __shared__ float As[16*132];   // [k][m] transposed
  __shared__ float Bs[16*132];   // [k][n]
  const int tid = threadIdx.x;
  const int tx = tid & 15, ty = tid >> 4;
  const int bm = blockIdx.y*128, bn = blockIdx.x*128;
  float acc[8][8] = {};
  for (int k0 = 0; k0 < DD; k0 += 16){
    #pragma unroll
    for (int p = 0; p < 2; ++p){
      int chunk = p*256 + tid;        // 0..511
      int m = chunk >> 2, c = chunk & 3;
      float v0,v1,v2,v3;
      if (A_RAW){
        size_t o = (size_t)(bm+m)*DD + k0 + c*4;
        v0=ldf(Ap,o,f); v1=ldf(Ap,o+1,f); v2=ldf(Ap,o+2,f); v3=ldf(Ap,o+3,f);
      } else {
        const float* a = (const float*)Ap + (size_t)(bm+m)*DD + k0 + c*4;
        v0=a[0]; v1=a[1]; v2=a[2]; v3=a[3];
      }
      As[(c*4+0)*132+m]=v0; As[(c*4+1)*132+m]=v1; As[(c*4+2)*132+m]=v2; As[(c*4+3)*132+m]=v3;
      size_t ow = (size_t)(bn+m)*DD + k0 + c*4;
      Bs[(c*4+0)*132+m]=ldf(W,ow,f);   Bs[(c*4+1)*132+m]=ldf(W,ow+1,f);
      Bs[(c*4+2)*132+m]=ldf(W,ow+2,f); Bs[(c*4+3)*132+m]=ldf(W,ow+3,f);
    }
    __syncthreads();
    #pragma unroll
    for (int kk = 0; kk < 16; ++kk){
      const float4* Av = (const float4*)&As[kk*132 + ty*8];
      const float4* Bv = (const float4*)&Bs[kk*132 + tx*8];
      float4 a0 = Av[0], a1 = Av[1], b0 = Bv[0], b1 = Bv[1];
      float a[8] = {a0.x,a0.y,a0.z,a0.w,a1.x,a1.y,a1.z,a1.w};
      float b[8] = {b0.x,b0.y,b0.z,b0.w,b1.x,b1.y,b1.z,b1.w};
      #pragma unroll
      for (int i = 0; i < 8; ++i)
        #pragma unroll
        for (int j = 0; j < 8; ++j)
          acc[i][j] = fmaf(a[i], b[j], acc[i][j]);
    }
    __syncthreads();
  }
  #pragma unroll
  for (int i = 0; i < 8; ++i)
    #pragma unroll
    for (int j = 0; j < 8; ++j){
      int m = bm + ty*8 + i, n = bn + tx*8 + j;
      float v = acc[i][j] + ldf(bias, n, f);
      if (RELU && v < 0.f) v = 0.f;
      C[(size_t)m*OUTW + n] = v;
    }
}

// ---------------- np.linalg.norm emulation — one WAVE per row, bit-exact tree ----------------
__global__ void __launch_bounds__(256)
norm_np_kernel(float* emb, __hip_bfloat16* embbf){
  const int wave = threadIdx.x >> 6, lane = threadIdx.x & 63;
  const int row = blockIdx.x*4 + wave;
  float* h = emb + (size_t)row*DD;
  __hip_bfloat16* hb = embbf + (size_t)row*DD;
  const int b = lane >> 4, l = lane & 15;
  const float* a = h + b*128;
  float s0 = a[l]      * a[l],       s4 = a[64+l]  * a[64+l];
  float s1 = a[16+l]   * a[16+l],    s5 = a[80+l]  * a[80+l];
  float s2 = a[32+l]   * a[32+l],    s6 = a[96+l]  * a[96+l];
  float s3 = a[48+l]   * a[48+l],    s7 = a[112+l] * a[112+l];
  float t = ((s0+s4) + (s1+s5)) + ((s2+s6) + (s3+s7));
  t += __shfl_down(t, 8);
  t += __shfl_down(t, 4);
  t += __shfl_down(t, 2);
  t += __shfl_down(t, 1);          // lane 16b now holds B[b]
  float B0 = __shfl(t, 0), B1 = __shfl(t, 16), B2 = __shfl(t, 32), B3 = __shfl(t, 48);
  float total = (B0+B1) + (B2+B3);
  float nrm = fmaxf(sqrtf(total), 1e-12f);
  for (int k = lane; k < DD; k += 64){
    float v = h[k] / nrm;
    h[k] = v;
    hb[k] = __float2bfloat16(v);
  }
}

// ---------------- bf16 MFMA S-prefilter, global_load_lds staging + LDS-staged epilogue ----------
__global__ void __launch_bounds__(256)
s_gemm_mfma(const unsigned short* embB, __hip_bfloat16* Sap, int row0){
  __shared__ unsigned short lds[128*132];      // 33.8 KB: staging (8K shorts) then C-tile
  unsigned short* Asm = lds;                   // 128*32
  unsigned short* Bsm = lds + 128*32;          // 128*32
  const int tid = threadIdx.x;
  const int wave = tid >> 6, lane = tid & 63;
  const int wm = (wave & 1) * 64, wn = (wave >> 1) * 64;
  const int bm = blockIdx.y * 128, bn = blockIdx.x * 128;
  const int lm = lane & 15, kg = lane >> 4;
  const int ml = lane >> 2;
  const int clog = (lane & 3) ^ (ml & 3);
  const size_t gA0 = (size_t)(row0 + bm + 32*wave + ml)*DD + clog*8;
  const size_t gB0 = (size_t)(       bn + 32*wave + ml)*DD + clog*8;
  unsigned short* lA = &Asm[(32*wave)*32];
  unsigned short* lB = &Bsm[(32*wave)*32];
  f32x4 acc[4][4] = {};
  for (int k0 = 0; k0 < DD; k0 += 32){
    async_lds16(embB + gA0 + k0,          lA);
    async_lds16(embB + gA0 + 16*DD + k0,  lA + 16*32);
    async_lds16(embB + gB0 + k0,          lB);
    async_lds16(embB + gB0 + 16*DD + k0,  lB + 16*32);
    __syncthreads();
    bf16x8 af[4], bfr[4];
    #pragma unroll
    for (int i = 0; i < 4; ++i){
      int r = wm + i*16 + lm;
      af[i] = *(const bf16x8*)&Asm[r*32 + ((kg ^ (r&3))*8)];
    }
    #pragma unroll
    for (int j = 0; j < 4; ++j){
      int r = wn + j*16 + lm;
      bfr[j] = *(const bf16x8*)&Bsm[r*32 + ((kg ^ (r&3))*8)];
    }
    #pragma unroll
    for (int i = 0; i < 4; ++i)
      #pragma unroll
      for (int j = 0; j < 4; ++j)
        acc[i][j] = __builtin_amdgcn_mfma_f32_16x16x32_bf16(af[i], bfr[j], acc[i][j], 0, 0, 0);
    __syncthreads();
  }
  // stage C-tile in LDS (stride 132), then vectorized global stores
  const int crow = kg * 4;
  #pragma unroll
  for (int i = 0; i < 4; ++i)
    #pragma unroll
    for (int j = 0; j < 4; ++j)
      #pragma unroll
      for (int r = 0; r < 4; ++r){
        __hip_bfloat16 b = __float2bfloat16(acc[i][j][r]);
        lds[(wm + i*16 + crow + r)*132 + wn + j*16 + lm] = *(unsigned short*)&b;
      }
  __syncthreads();
  const int rr = tid >> 1, half = (tid & 1) * 64;
  const unsigned short* src = &lds[rr*132 + half];
  unsigned short* dst = (unsigned short*)Sap + (size_t)(bm + rr)*NN + bn + half;
  #pragma unroll
  for (int q = 0; q < 8; ++q)
    *(u16x8*)(dst + q*8) = *(const u16x8*)(src + q*8);
}

// ---------------- candidate selection: vectorized loads + 12-bit hist + refinement ----------
__global__ void __launch_bounds__(256)
cand_kernel(const __hip_bfloat16* Sap, int row0, int* cand, int* cand_cnt){
  __shared__ int hist[4096];
  __shared__ int partial[256];
  __shared__ int subhist[16];
  __shared__ int sh_T, sh_ST, sh_cab, sh_cnt;
  const int rl = blockIdx.x, tid = threadIdx.x;
  const unsigned short* srow = (const unsigned short*)Sap + (size_t)rl*NN;
  for (int b = tid; b < 4096; b += 256) hist[b] = 0;
  if (tid < 16) subhist[tid] = 0;
  if (tid == 0) sh_cnt = 0;
  __syncthreads();
  unsigned short uv[32];
  const u16x8* srow8 = (const u16x8*)(srow + tid*32);   // thread owns 32 contiguous elems
  #pragma unroll
  for (int q = 0; q < 4; ++q){
    u16x8 v = srow8[q];
    #pragma unroll
    for (int e = 0; e < 8; ++e){
      unsigned short u = v[e];
      uv[q*8+e] = (unsigned short)(u ^ ((u & 0x8000u) ? 0xFFFFu : 0x8000u));  // order-preserving
      atomicAdd(&hist[uv[q*8+e] >> 4], 1);
    }
  }
  __syncthreads();
  int ps = 0;
  #pragma unroll
  for (int b = 0; b < 16; ++b) ps += hist[tid*16 + b];
  partial[tid] = ps;
  __syncthreads();
  if (tid == 0){
    int c = 0, t = 255;
    for (; t > 0; --t){ if (c + partial[t] >= CTARGET) break; c += partial[t]; }
    int T = t*16;
    for (int b = 15; b >= 0; --b){
      int h = hist[t*16 + b];
      if (c + h >= CTARGET){ T = t*16 + b; break; }
      c += h;
    }
    sh_T = T; sh_cab = c;          // count strictly above bucket T
  }
  __syncthreads();
  const int T = sh_T;
  #pragma unroll
  for (int m = 0; m < 32; ++m)
    if ((uv[m] >> 4) == T) atomicAdd(&subhist[uv[m] & 15], 1);
  __syncthreads();
  if (tid == 0){
    int c = sh_cab, st = 0;
    for (int s2 = 15; s2 >= 0; --s2){ c += subhist[s2]; if (c >= CTARGET){ st = s2; break; } }
    sh_ST = st;
  }
  __syncthreads();
  const int ST = sh_ST;
  #pragma unroll
  for (int m = 0; m < 32; ++m){
    int hi = uv[m] >> 4;
    bool keep = (hi > T) || (hi == T && (uv[m] & 15) >= ST);
    if (keep){
      int pos = atomicAdd(&sh_cnt, 1);
      if (pos < CCAP) cand[(size_t)(row0+rl)*CCAP + pos] = tid*32 + m;
    }
  }
  __syncthreads();
  if (tid == 0) cand_cnt[row0+rl] = (sh_cnt < CCAP) ? sh_cnt : CCAP;
}

// ---------------- exact fp32-chain rescore, j-bucketed for L2 residency ----------------
__global__ void __launch_bounds__(256)
rescore_pass(const float* emb, const int* cand, const int* cand_cnt, float* sval, int pass){
  __shared__ float ea[DD];
  const int row = blockIdx.x, tid = threadIdx.x;
  for (int k = tid; k < DD; k += 256) ea[k] = emb[(size_t)row*DD + k];
  const int cnt = cand_cnt[row];
  __syncthreads();
  for (int c = tid; c < cnt; c += 256){
    int j = cand[(size_t)row*CCAP + c];
    if ((j >> 11) != pass) continue;           // 4MB emb slice per pass
    const float4* eb = (const float4*)(emb + (size_t)j*DD);
    float acc = 0.f;
    #pragma unroll 8
    for (int k4 = 0; k4 < DD/4; ++k4){
      float4 v = eb[k4];
      acc = fmaf(ea[k4*4+0], v.x, acc);        // exact np chain, k ascending
      acc = fmaf(ea[k4*4+1], v.y, acc);
      acc = fmaf(ea[k4*4+2], v.z, acc);
      acc = fmaf(ea[k4*4+3], v.w, acc);
    }
    sval[(size_t)row*CCAP + c] = acc;
  }
}

// ---------------- final top-31: bitonic over 128 keys (value desc, index asc) ----------------
__global__ void __launch_bounds__(128)
select_topk(const float* sval, const int* cand, const int* cand_cnt, float* tv, int* ti){
  __shared__ unsigned long long keys[CCAP];
  const int row = blockIdx.x, tid = threadIdx.x;
  const int cnt = cand_cnt[row];
  unsigned long long key = 0ull;
  if (tid < cnt){
    int j = cand[(size_t)row*CCAP + tid];
    unsigned u = __float_as_uint(sval[(size_t)row*CCAP + tid]);
    u = (u & 0x80000000u) ? ~u : (u | 0x80000000u);
    key = ((unsigned long long)u << 32) | (unsigned long long)(0xFFFFFFFFu - (unsigned)j);
  }
  keys[tid] = key;
  __syncthreads();
  for (int kk = 2; kk <= CCAP; kk <<= 1){
    for (int jj = kk >> 1; jj > 0; jj >>= 1){
      int l = tid ^ jj;
      if (l > tid){
        unsigned long long a = keys[tid], b = keys[l];
        bool up = (tid & kk) == 0;             // descending
        if (up ? (a < b) : (a > b)){ keys[tid] = b; keys[l] = a; }
      }
      __syncthreads();
    }
  }
  if (tid < KK){
    unsigned long long k2 = keys[tid];
    unsigned u  = (unsigned)(k2 >> 32);
    unsigned uj = 0xFFFFFFFFu - (unsigned)(k2 & 0xFFFFFFFFull);
    unsigned fv = (u & 0x80000000u) ? (u ^ 0x80000000u) : ~u;
    tv[(size_t)row*KK + tid] = __uint_as_float(fv);
    ti[(size_t)row*KK + tid] = (int)uj;
  }
}

// ---------------- edge-list processing ----------------
__global__ void deg_count_kernel(const float* tv, const int* ti, double* deg, int* in_count){
  int e = blockIdx.x*256 + threadIdx.x;
  if (e >= NE) return;
  int i = e / KK;
  int j = ti[e];
  float s = tv[e]; if (s < 0.f) s = 0.f;
  double h = 0.5 * (double)s;
  atomicAdd(&deg[i], h);
  atomicAdd(&deg[j], h);
  atomicAdd(&in_count[j], 1);
}

// single block: dinv (parallel) + in_off exclusive scan
__global__ void scan_dinv_kernel(const int* in_count, int* in_off, const double* deg, double* dinv){
  __shared__ int part[256];
  const int tid = threadIdx.x;
  for (int i = tid; i < NN; i += 256) dinv[i] = 1.0 / (sqrt(deg[i]) + 1e-10);
  const int base = tid * 32;
  int local[32], sum = 0;
  for (int m = 0; m < 32; ++m){ local[m] = sum; sum += in_count[base + m]; }
  part[tid] = sum; __syncthreads();
  if (tid == 0){ int acc = 0; for (int t = 0; t < 256; ++t){ int p = part[t]; part[t] = acc; acc += p; } }
  __syncthreads();
  const int off = part[tid];
  for (int m = 0; m < 32; ++m) in_off[base + m] = off + local[m];
  if (tid == 255) in_off[NN] = NE;
}

__global__ void fill_kernel(const float* tv, const int* ti, const double* dinv,
                            const int* in_off, int* cursor, int* in_src, float* in_w, float* own_w){
  int e = blockIdx.x*256 + threadIdx.x;
  if (e >= NE) return;
  int i = e / KK;
  int j = ti[e];
  float s = tv[e]; if (s < 0.f) s = 0.f;
  float w = (float)(0.5 * (double)s * dinv[i] * dinv[j]);
  own_w[e] = w;
  int pos = atomicAdd(&cursor[j], 1);
  in_src[in_off[j] + pos] = i;
  in_w [in_off[j] + pos] = w;
}

// ---------------- dense adj: one block per row, LDS merge, vectorized stores ----------------
__global__ void dense_fill(const int* ti, const float* own_w, const int* in_off,
                           const int* in_src, const float* in_w,
                           void* outp, const int* flagp){
  __shared__ float row[NN];
  const int f = *flagp;
  const int i = blockIdx.x, tid = threadIdx.x;
  for (int c = tid*4; c < NN; c += 1024) *(float4*)&row[c] = make_float4(0.f,0.f,0.f,0.f);
  __syncthreads();
  if (tid < KK)
    atomicAdd(&row[ti[(size_t)i*KK + tid]], own_w[(size_t)i*KK + tid]);
  const int p1 = in_off[i+1];
  for (int p = in_off[i] + tid; p < p1; p += 256)
    atomicAdd(&row[in_src[p]], in_w[p]);
  __syncthreads();
  if (f){
    float* adj = (float*)outp + (size_t)NN*OO + (size_t)i*NN;
    for (int c = tid*4; c < NN; c += 1024) *(float4*)&adj[c] = *(float4*)&row[c];
  } else {
    __hip_bfloat16* adj = (__hip_bfloat16*)outp + (size_t)NN*OO + (size_t)i*NN;
    for (int c = tid*8; c < NN; c += 2048){
      unsigned u[8];
      #pragma unroll
      for (int q = 0; q < 8; ++q){
        __hip_bfloat16 b = __float2bfloat16(row[c+q]);
        u[q] = *(unsigned short*)&b;
      }
      uint4 o;
      o.x = u[0] | (u[1]<<16); o.y = u[2] | (u[3]<<16);
      o.z = u[4] | (u[5]<<16); o.w = u[6] | (u[7]<<16);
      *(uint4*)&adj[c] = o;
    }
  }
}

// ---------------- GCN tail ----------------
__global__ void spmm1_kernel(const float* xw0, const float* own_w, const int* ti,
                             const int* in_off, const int* in_src, const float* in_w, float* x1){
  const int i = blockIdx.x, c = threadIdx.x;
  float acc = 0.f;
  const int*   oi = ti    + (size_t)i*KK;
  const float* ow = own_w + (size_t)i*KK;
  for (int m = 0; m < KK; ++m)
    acc = fmaf(ow[m], xw0[(size_t)oi[m]*HH + c], acc);
  const int p0 = in_off[i], p1 = in_off[i+1];
  for (int p = p0; p < p1; ++p)
    acc = fmaf(in_w[p], xw0[(size_t)in_src[p]*HH + c], acc);
  x1[(size_t)i*HH + c] = acc > 0.f ? acc : 0.f;
}

__global__ void gemm_xw1(const float* x1, const void* W1, const void* b1,
                         float* xw1, const int* flagp){
  const int f = *flagp;
  __shared__ float xs[16][257];
  __shared__ float ws[16][257];
  const int tid = threadIdx.x;
  const int row0 = blockIdx.x * 16;
  for (int t = tid; t < 16*256; t += 256){
    int r = t >> 8, k = t & 255;
    xs[r][k] = x1[(size_t)(row0 + r)*HH + k];
    ws[r][k] = ldf(W1, (size_t)r*HH + k, f);
  }
  __syncthreads();
  const int r = tid >> 4, c = tid & 15;
  float a = 0.f;
  #pragma unroll 8
  for (int k = 0; k < HH; ++k) a = fmaf(xs[r][k], ws[c][k], a);
  xw1[(size_t)(row0 + r)*OO + c] = a + ldf(b1, c, f);
}

// 4 rows per 64-thread block: r = tid>>4, c = tid&15
__global__ void spmm2_kernel(const float* xw1, const float* own_w, const int* ti,
                             const int* in_off, const int* in_src, const float* in_w,
                             void* outp, const int* flagp){
  const int i = blockIdx.x*4 + (threadIdx.x >> 4);
  const int c = threadIdx.x & 15;
  const int f = *flagp;
  float acc = 0.f;
  const int*   oi = ti    + (size_t)i*KK;
  const float* ow = own_w + (size_t)i*KK;
  for (int m = 0; m < KK; ++m)
    acc = fmaf(ow[m], xw1[(size_t)oi[m]*OO + c], acc);
  const int p0 = in_off[i], p1 = in_off[i+1];
  for (int p = p0; p < p1; ++p)
    acc = fmaf(in_w[p], xw1[(size_t)in_src[p]*OO + c], acc);
  if (f) ((float*)outp)[(size_t)i*OO + c] = acc;
  else   ((__hip_bfloat16*)outp)[(size_t)i*OO + c] = __float2bfloat16(acc);
}

extern "C" void kernel_launch(void* const* d_in, const int* in_sizes, int n_in,
                              void* d_out, int out_size, void* d_ws, size_t ws_size,
                              hipStream_t stream) {
  (void)in_sizes; (void)n_in; (void)out_size; (void)ws_size;
  const void* features = d_in[0];
  const void* x        = d_in[1];
  const void* gsl_W0   = d_in[2];
  const void* gsl_b0   = d_in[3];
  const void* gsl_W1   = d_in[4];
  const void* gsl_b1   = d_in[5];
  const void* gcn_W0   = d_in[6];
  const void* gcn_b0   = d_in[7];
  const void* gcn_W1   = d_in[8];
  const void* gcn_b1   = d_in[9];

  // Big scratch inside the adj half of d_out (fully rewritten by dense_fill at the end).
  char* base = (char*)d_out + ((size_t)512 << 10);
  float*          h1    = (float*)(base);                               // 16MB, dead after mlp2
  float*          emb   = (float*)(base + ((size_t)16 << 20));          // 16MB, dead after rescore
  __hip_bfloat16* embbf = (__hip_bfloat16*)(base + ((size_t)32 << 20)); // 8MB
  __hip_bfloat16* Sap   = (__hip_bfloat16*)(base + ((size_t)40 << 20)); // 64MB (per 4096-row batch)
  float*          tv    = (float*)(base + ((size_t)104 << 20));         // 1MB, dead after fill
  int*            cand  = (int*)  (base + ((size_t)105 << 20));         // 4MB (8192x128)
  float*          sval  = (float*)(base + ((size_t)109 << 20));         // 4MB
  int*            ccnt  = (int*)  (base + ((size_t)113 << 20));         // 32KB
  char*           misc  =          base + ((size_t)114 << 20);          // ends ~114.2MB < 134MB
  double* deg      = (double*)(misc);
  double* dinv     = (double*)(misc + 0x10000);
  int*    in_count = (int*)   (misc + 0x20000);
  int*    cursor   = (int*)   (misc + 0x28000);
  float*  xw0 = (float*)(base);                       // 8MB  (reuses h1, after rescore)
  float*  x1  = (float*)(base + ((size_t)8  << 20));  // 8MB
  float*  xw1 = (float*)(base + ((size_t)16 << 20));  // 0.5MB (reuses emb, dead by then)

  // d_ws (~4.096MB): arrays surviving until dense_fill, + flag
  char* sm = (char*)d_ws;
  int*   ti     = (int*)sm;    sm += (size_t)4*NE;
  float* own_w  = (float*)sm;  sm += (size_t)4*NE;
  int*   in_src = (int*)sm;    sm += (size_t)4*NE;
  float* in_w   = (float*)sm;  sm += (size_t)4*NE;
  int*   in_off = (int*)sm;    sm += (size_t)4*(NN+1);
  int*   flagp  = (int*)sm;    sm += 4;

  init_kernel<<<dim3(33), dim3(256), 0, stream>>>(features, flagp, deg, in_count, cursor);

  // GSL MLP — emulated numpy float32 semantics (ascending-FMA chains)
  gemm_nt_f32<true,  true,  DD><<<dim3(4,64), dim3(256), 0, stream>>>(features, gsl_W0, gsl_b0, h1,  flagp);
  gemm_nt_f32<false, false, DD><<<dim3(4,64), dim3(256), 0, stream>>>(h1,       gsl_W1, gsl_b1, emb, flagp);
  norm_np_kernel<<<dim3(NN/4), dim3(256), 0, stream>>>(emb, embbf);

  // bf16-MFMA prefilter + candidate selection, batched (4096 rows / batch)
  for (int b = 0; b < NN/SBATCH; ++b){
    const int row0 = b * SBATCH;
    s_gemm_mfma<<<dim3(NN/128, SBATCH/128), dim3(256), 0, stream>>>((const unsigned short*)embbf, Sap, row0);
    cand_kernel<<<dim3(SBATCH), dim3(256), 0, stream>>>(Sap, row0, cand, ccnt);
  }
  // exact rescore (4 L2-resident passes) + final selection
  for (int p = 0; p < 4; ++p)
    rescore_pass<<<dim3(NN), dim3(256), 0, stream>>>(emb, cand, ccnt, sval, p);
  select_topk<<<dim3(NN), dim3(128), 0, stream>>>(sval, cand, ccnt, tv, ti);

  // graph assembly
  const int eb = (NE + 255)/256;
  deg_count_kernel<<<dim3(eb), dim3(256), 0, stream>>>(tv, ti, deg, in_count);
  scan_dinv_kernel<<<dim3(1), dim3(256), 0, stream>>>(in_count, in_off, deg, dinv);
  fill_kernel<<<dim3(eb), dim3(256), 0, stream>>>(tv, ti, dinv, in_off, cursor, in_src, in_w, own_w);

  // GCN (fp32, sparse adj) — writes outx
  gemm_nt_f32<true, false, HH><<<dim3(2,64), dim3(256), 0, stream>>>(x, gcn_W0, gcn_b0, xw0, flagp);
  spmm1_kernel<<<dim3(NN), dim3(256), 0, stream>>>(xw0, own_w, ti, in_off, in_src, in_w, x1);
  gemm_xw1<<<dim3(NN/16), dim3(256), 0, stream>>>(x1, gcn_W1, gcn_b1, xw1, flagp);
  spmm2_kernel<<<dim3(NN/4), dim3(64), 0, stream>>>(xw1, own_w, ti, in_off, in_src, in_w, d_out, flagp);

  // dense adj last: reads only d_ws
  dense_fill<<<dim3(NN), dim3(256), 0, stream>>>(ti, own_w, in_off, in_src, in_w, d_out, flagp);
}